// Round 1
// baseline (128.891 us; speedup 1.0000x reference)
//
#include <hip/hip_runtime.h>

// ParameterMixture: weight_mixture[b,o,i] = sum_k wp[b,k] * wbank[widx[b,k],o,i]
//                   bias_mixture[b,o]     = sum_k bp[b,k] * bbank[bidx[b,k],o]
// E=64, K=8, B=32, O=I=1024. All fp32. Memory-bound gather-reduce.

constexpr int E = 64;
constexpr int K = 8;
constexpr int B = 32;
constexpr int IN_DIM = 1024;
constexpr int OUT_DIM = 1024;

constexpr int WM_ELEMS   = B * OUT_DIM * IN_DIM;       // 33,554,432 floats (output 0)
constexpr int NV4_PER_B  = OUT_DIM * IN_DIM / 4;       // 262,144 float4 per batch
constexpr int BLK        = 256;
constexpr int WBLK_PER_B = NV4_PER_B / BLK;            // 1024 blocks per batch
constexpr int WBLOCKS    = WBLK_PER_B * B;             // 32,768 weight blocks
constexpr int BIAS_V4    = B * OUT_DIM / 4;            // 8,192 float4
constexpr int BIAS_BLOCKS = BIAS_V4 / BLK;             // 32 bias blocks

__global__ __launch_bounds__(BLK) void ParameterMixture_86835648790543_kernel(
    const float* __restrict__ wprobs,   // [B,K]
    const float* __restrict__ bprobs,   // [B,K]
    const int*   __restrict__ widx,     // [B,K]
    const int*   __restrict__ bidx,     // [B,K]
    const float* __restrict__ wbank,    // [E,O,I]
    const float* __restrict__ bbank,    // [E,O]
    float*       __restrict__ out)      // [B*O*I] ++ [B*O]
{
    const int bid = blockIdx.x;

    if (bid < WBLOCKS) {
        // Chunk-major ordering: consecutive blocks cover the SAME offset slice
        // across all 32 batches -> live read working set per slice is at most
        // 64 experts x 4KB = 256KB -> L2/L3 collapse the 4x logical reuse.
        const int chunk = bid / B;          // 0..1023  (which 4KB slice)
        const int b     = bid % B;          // 0..31    (which batch)

        __shared__ float sp[K];
        __shared__ int   se[K];
        if (threadIdx.x < K) {
            sp[threadIdx.x] = wprobs[b * K + threadIdx.x];
            se[threadIdx.x] = widx[b * K + threadIdx.x];
        }
        __syncthreads();

        const int off4 = chunk * BLK + threadIdx.x;   // float4 index within a matrix
        const float4* __restrict__ bank4 = (const float4*)wbank;

        float4 acc = make_float4(0.f, 0.f, 0.f, 0.f);
#pragma unroll
        for (int k = 0; k < K; ++k) {
            const float  p = sp[k];
            const float4 v = bank4[(size_t)se[k] * NV4_PER_B + off4];
            acc.x += p * v.x;
            acc.y += p * v.y;
            acc.z += p * v.z;
            acc.w += p * v.w;
        }
        ((float4*)out)[(size_t)b * NV4_PER_B + off4] = acc;
    } else {
        // Bias mixture tail: 32 blocks, one float4 of bias output per thread.
        const int t = (bid - WBLOCKS) * BLK + threadIdx.x;  // float4 idx into [B,O]
        const int b    = t / (OUT_DIM / 4);
        const int off4 = t % (OUT_DIM / 4);

        const float4* __restrict__ bb4 = (const float4*)bbank;
        float4 acc = make_float4(0.f, 0.f, 0.f, 0.f);
#pragma unroll
        for (int k = 0; k < K; ++k) {
            const float p = bprobs[b * K + k];
            const int   e = bidx[b * K + k];
            const float4 v = bb4[e * (OUT_DIM / 4) + off4];
            acc.x += p * v.x;
            acc.y += p * v.y;
            acc.z += p * v.z;
            acc.w += p * v.w;
        }
        ((float4*)(out + WM_ELEMS))[t] = acc;
    }
}

extern "C" void kernel_launch(void* const* d_in, const int* in_sizes, int n_in,
                              void* d_out, int out_size, void* d_ws, size_t ws_size,
                              hipStream_t stream) {
    const float* wprobs = (const float*)d_in[0];
    const float* bprobs = (const float*)d_in[1];
    const int*   widx   = (const int*)d_in[2];
    const int*   bidx   = (const int*)d_in[3];
    const float* wbank  = (const float*)d_in[4];
    const float* bbank  = (const float*)d_in[5];
    float*       out    = (float*)d_out;

    const int grid = WBLOCKS + BIAS_BLOCKS;
    ParameterMixture_86835648790543_kernel<<<grid, BLK, 0, stream>>>(
        wprobs, bprobs, widx, bidx, wbank, bbank, out);
}

// Round 2
// 123.177 us; speedup vs baseline: 1.0464x; 1.0464x over previous
//
#include <hip/hip_runtime.h>

// ParameterMixture, expert-major formulation:
//   weight_mixture[b,:,:] = sum_e P[e][b] * wbank[e,:,:]   where
//   P[e][b] = sum_k wprobs[b,k] * (widx[b,k]==e)   (dense 64x32, precomputed)
// Each weight block owns one 4KB offset-slice and accumulates ALL 32 batches,
// so every byte of wbank is fetched from HBM exactly once (256 MB reads,
// 128 MB writes -> ~62us roofline).

constexpr int E = 64;
constexpr int K = 8;
constexpr int B = 32;
constexpr int IN_DIM = 1024;
constexpr int OUT_DIM = 1024;

constexpr int NV4       = OUT_DIM * IN_DIM / 4;   // 262,144 float4 per expert matrix
constexpr int BLK       = 256;
constexpr int WCHUNKS   = NV4 / BLK;              // 1024 weight blocks
constexpr int WM_ELEMS  = B * OUT_DIM * IN_DIM;   // output-0 floats
constexpr int BIAS_V4   = B * OUT_DIM / 4;        // 8192
constexpr int BIAS_BLOCKS = BIAS_V4 / BLK;        // 32
constexpr int WS_NEEDED = E * B * (int)sizeof(float);  // 8 KB dense prob matrix

// ---- kernel A: build dense expert-major prob matrix P[e][b] in d_ws ----
__global__ void ParameterMixture_dense_probs(
    const float* __restrict__ wprobs, const int* __restrict__ widx,
    float* __restrict__ P)
{
    const int t = blockIdx.x * blockDim.x + threadIdx.x;   // 0..2047
    if (t >= E * B) return;
    const int e = t >> 5;      // expert
    const int b = t & 31;      // batch
    float s = 0.f;
#pragma unroll
    for (int k = 0; k < K; ++k)
        s += (widx[b * K + k] == e) ? wprobs[b * K + k] : 0.f;
    P[t] = s;   // P[e*B + b]
}

// ---- kernel B: main mixture ----
__global__ __launch_bounds__(BLK) void ParameterMixture_86835648790543_kernel(
    const float* __restrict__ wbank,    // [E,O,I]
    const float* __restrict__ P,        // [E,B] dense probs (d_ws)
    const float* __restrict__ bprobs,   // [B,K]
    const int*   __restrict__ bidx,     // [B,K]
    const float* __restrict__ bbank,    // [E,O]
    float*       __restrict__ out)      // [B*O*I] ++ [B*O]
{
    const int bid = blockIdx.x;

    if (bid < WCHUNKS) {
        const int off4 = bid * BLK + threadIdx.x;       // float4 index in a matrix
        const float4* __restrict__ bank4 = (const float4*)wbank;

        float4 acc[B];
#pragma unroll
        for (int b = 0; b < B; ++b) acc[b] = make_float4(0.f, 0.f, 0.f, 0.f);

        // depth-1 software pipeline over experts; each slice streamed once.
        float4 v = bank4[(size_t)0 * NV4 + off4];
#pragma unroll 1
        for (int e = 0; e < E; ++e) {
            const int en = (e + 1 < E) ? e + 1 : e;
            float4 vn = bank4[(size_t)en * NV4 + off4];   // prefetch next slice
            const float* __restrict__ pe = P + e * B;     // wave-uniform -> s_load
#pragma unroll
            for (int b = 0; b < B; ++b) {
                const float p = pe[b];
                acc[b].x += p * v.x;
                acc[b].y += p * v.y;
                acc[b].z += p * v.z;
                acc[b].w += p * v.w;
            }
            v = vn;
        }

        float4* __restrict__ out4 = (float4*)out;
#pragma unroll
        for (int b = 0; b < B; ++b)
            out4[(size_t)b * NV4 + off4] = acc[b];
    } else {
        // bias mixture tail: 32 blocks, one float4 of [B,O] per thread
        const int t    = (bid - WCHUNKS) * BLK + threadIdx.x;
        const int b    = t / (OUT_DIM / 4);
        const int off4 = t % (OUT_DIM / 4);

        const float4* __restrict__ bb4 = (const float4*)bbank;
        float4 acc = make_float4(0.f, 0.f, 0.f, 0.f);
#pragma unroll
        for (int k = 0; k < K; ++k) {
            const float p = bprobs[b * K + k];
            const int   e = bidx[b * K + k];
            const float4 v = bb4[e * (OUT_DIM / 4) + off4];
            acc.x += p * v.x;
            acc.y += p * v.y;
            acc.z += p * v.z;
            acc.w += p * v.w;
        }
        ((float4*)(out + WM_ELEMS))[t] = acc;
    }
}

// ---- fallback (round-1 kernel) if d_ws is too small for the dense matrix ----
__global__ __launch_bounds__(BLK) void ParameterMixture_fallback(
    const float* __restrict__ wprobs, const float* __restrict__ bprobs,
    const int* __restrict__ widx, const int* __restrict__ bidx,
    const float* __restrict__ wbank, const float* __restrict__ bbank,
    float* __restrict__ out)
{
    const int bid = blockIdx.x;
    if (bid < WCHUNKS * B) {
        const int chunk = bid / B;
        const int b     = bid % B;
        __shared__ float sp[K];
        __shared__ int   se[K];
        if (threadIdx.x < K) {
            sp[threadIdx.x] = wprobs[b * K + threadIdx.x];
            se[threadIdx.x] = widx[b * K + threadIdx.x];
        }
        __syncthreads();
        const int off4 = chunk * BLK + threadIdx.x;
        const float4* __restrict__ bank4 = (const float4*)wbank;
        float4 acc = make_float4(0.f, 0.f, 0.f, 0.f);
#pragma unroll
        for (int k = 0; k < K; ++k) {
            const float  p = sp[k];
            const float4 v = bank4[(size_t)se[k] * NV4 + off4];
            acc.x += p * v.x; acc.y += p * v.y; acc.z += p * v.z; acc.w += p * v.w;
        }
        ((float4*)out)[(size_t)b * NV4 + off4] = acc;
    } else {
        const int t    = (bid - WCHUNKS * B) * BLK + threadIdx.x;
        const int b    = t / (OUT_DIM / 4);
        const int off4 = t % (OUT_DIM / 4);
        const float4* __restrict__ bb4 = (const float4*)bbank;
        float4 acc = make_float4(0.f, 0.f, 0.f, 0.f);
#pragma unroll
        for (int k = 0; k < K; ++k) {
            const float p = bprobs[b * K + k];
            const int   e = bidx[b * K + k];
            const float4 v = bb4[e * (OUT_DIM / 4) + off4];
            acc.x += p * v.x; acc.y += p * v.y; acc.z += p * v.z; acc.w += p * v.w;
        }
        ((float4*)(out + WM_ELEMS))[t] = acc;
    }
}

extern "C" void kernel_launch(void* const* d_in, const int* in_sizes, int n_in,
                              void* d_out, int out_size, void* d_ws, size_t ws_size,
                              hipStream_t stream) {
    const float* wprobs = (const float*)d_in[0];
    const float* bprobs = (const float*)d_in[1];
    const int*   widx   = (const int*)d_in[2];
    const int*   bidx   = (const int*)d_in[3];
    const float* wbank  = (const float*)d_in[4];
    const float* bbank  = (const float*)d_in[5];
    float*       out    = (float*)d_out;

    if (ws_size >= (size_t)WS_NEEDED) {
        float* P = (float*)d_ws;
        ParameterMixture_dense_probs<<<(E * B + BLK - 1) / BLK, BLK, 0, stream>>>(
            wprobs, widx, P);
        ParameterMixture_86835648790543_kernel<<<WCHUNKS + BIAS_BLOCKS, BLK, 0, stream>>>(
            wbank, P, bprobs, bidx, bbank, out);
    } else {
        ParameterMixture_fallback<<<WCHUNKS * B + BIAS_BLOCKS, BLK, 0, stream>>>(
            wprobs, bprobs, widx, bidx, wbank, bbank, out);
    }
}

// Round 3
// 108.050 us; speedup vs baseline: 1.1929x; 1.1400x over previous
//
#include <hip/hip_runtime.h>

// ParameterMixture, expert-major, fully fused (no workspace dependence):
//   P[e][b] = sum_k wprobs[b,k]*(widx[b,k]==e)    (built in LDS per block)
//   weight_mixture[b,:,:] = sum_e P[e][b] * wbank[e,:,:]
// Each weight block owns one 4KB offset-slice (256 float4) and accumulates
// ALL 32 batch outputs in registers while streaming the 64 expert slices
// exactly once from HBM. Reads = 256 MB (wbank once), writes = 128 MB.
// Depth-2 software prefetch keeps 2 loads in flight per wave.

constexpr int E = 64;
constexpr int K = 8;
constexpr int B = 32;
constexpr int IN_DIM = 1024;
constexpr int OUT_DIM = 1024;

constexpr int NV4        = OUT_DIM * IN_DIM / 4;  // 262,144 float4 per expert
constexpr int BLK        = 256;
constexpr int WCHUNKS    = NV4 / BLK;             // 1024 weight blocks
constexpr int WM_ELEMS   = B * OUT_DIM * IN_DIM;  // output-0 floats
constexpr int OB4        = OUT_DIM / 4;           // 256 float4 per bias row
constexpr int BIAS_BLOCKS = (B * OB4) / BLK;      // 32

__global__ __launch_bounds__(BLK) void ParameterMixture_86835648790543_kernel(
    const float* __restrict__ wprobs,   // [B,K]
    const float* __restrict__ bprobs,   // [B,K]
    const int*   __restrict__ widx,     // [B,K]
    const int*   __restrict__ bidx,     // [B,K]
    const float* __restrict__ wbank,    // [E,O,I]
    const float* __restrict__ bbank,    // [E,O]
    float*       __restrict__ out)      // [B*O*I] ++ [B*O]
{
    const int bid = blockIdx.x;
    const int t   = threadIdx.x;

    if (bid < WCHUNKS) {
        // ---- build dense P[e][b] in LDS (e-major) ----
        __shared__ float sP[E * B];      // 8 KB
        __shared__ float swp[B * K];     // 1 KB
        __shared__ int   swi[B * K];     // 1 KB

        swp[t] = wprobs[t];              // B*K == 256 == BLK exactly
        swi[t] = widx[t];
        __syncthreads();

#pragma unroll
        for (int r = 0; r < (E * B) / BLK; ++r) {   // 8 entries per thread
            const int idx = r * BLK + t;
            const int e = idx >> 5;
            const int b = idx & 31;
            float s = 0.f;
#pragma unroll
            for (int k = 0; k < K; ++k)
                s += (swi[b * K + k] == e) ? swp[b * K + k] : 0.f;
            sP[idx] = s;
        }
        __syncthreads();

        // ---- stream experts, accumulate all 32 batches in registers ----
        const int off4 = bid * BLK + t;               // float4 index in a matrix
        const float4* __restrict__ bank4 = (const float4*)wbank;

        float4 acc[B];
#pragma unroll
        for (int b = 0; b < B; ++b) acc[b] = make_float4(0.f, 0.f, 0.f, 0.f);

        float4 v0 = bank4[(size_t)0 * NV4 + off4];
        float4 v1 = bank4[(size_t)1 * NV4 + off4];

#pragma unroll 1
        for (int e = 0; e < E; e += 2) {
            // depth-2 prefetch, clamped (re-reads last slice harmlessly at tail)
            const int e2 = (e + 2 < E) ? e + 2 : E - 1;
            const int e3 = (e + 3 < E) ? e + 3 : E - 1;
            float4 n0 = bank4[(size_t)e2 * NV4 + off4];
            float4 n1 = bank4[(size_t)e3 * NV4 + off4];

            const float4* __restrict__ p0 = (const float4*)&sP[e * B];
            const float4* __restrict__ p1 = (const float4*)&sP[(e + 1) * B];

#pragma unroll
            for (int bq = 0; bq < B / 4; ++bq) {
                const float4 pa = p0[bq];   // broadcast ds_read_b128
                const float4 pb = p1[bq];
#define ACC1(j, pc, vv)                                                       \
                acc[4 * bq + (j)].x += (pc) * (vv).x;                          \
                acc[4 * bq + (j)].y += (pc) * (vv).y;                          \
                acc[4 * bq + (j)].z += (pc) * (vv).z;                          \
                acc[4 * bq + (j)].w += (pc) * (vv).w;
                ACC1(0, pa.x, v0) ACC1(1, pa.y, v0) ACC1(2, pa.z, v0) ACC1(3, pa.w, v0)
                ACC1(0, pb.x, v1) ACC1(1, pb.y, v1) ACC1(2, pb.z, v1) ACC1(3, pb.w, v1)
#undef ACC1
            }
            v0 = n0;
            v1 = n1;
        }

        float4* __restrict__ out4 = (float4*)out;
#pragma unroll
        for (int b = 0; b < B; ++b)
            out4[(size_t)b * NV4 + off4] = acc[b];
    } else {
        // ---- bias mixture tail: 32 blocks, one float4 of [B,O] per thread ----
        const int tt   = (bid - WCHUNKS) * BLK + t;
        const int b    = tt / OB4;
        const int off4 = tt % OB4;

        const float4* __restrict__ bb4 = (const float4*)bbank;
        float4 acc = make_float4(0.f, 0.f, 0.f, 0.f);
#pragma unroll
        for (int k = 0; k < K; ++k) {
            const float p = bprobs[b * K + k];
            const int   e = bidx[b * K + k];
            const float4 v = bb4[e * OB4 + off4];
            acc.x += p * v.x;
            acc.y += p * v.y;
            acc.z += p * v.z;
            acc.w += p * v.w;
        }
        ((float4*)(out + WM_ELEMS))[tt] = acc;
    }
}

extern "C" void kernel_launch(void* const* d_in, const int* in_sizes, int n_in,
                              void* d_out, int out_size, void* d_ws, size_t ws_size,
                              hipStream_t stream) {
    const float* wprobs = (const float*)d_in[0];
    const float* bprobs = (const float*)d_in[1];
    const int*   widx   = (const int*)d_in[2];
    const int*   bidx   = (const int*)d_in[3];
    const float* wbank  = (const float*)d_in[4];
    const float* bbank  = (const float*)d_in[5];
    float*       out    = (float*)d_out;

    ParameterMixture_86835648790543_kernel<<<WCHUNKS + BIAS_BLOCKS, BLK, 0, stream>>>(
        wprobs, bprobs, widx, bidx, wbank, bbank, out);
}

// Round 4
// 106.609 us; speedup vs baseline: 1.2090x; 1.0135x over previous
//
#include <hip/hip_runtime.h>

// ParameterMixture, expert-major dense mixture:
//   P[e][b] = sum_k wprobs[b,k]*(widx[b,k]==e)  (built once per block in LDS)
//   weight_mixture[b,:,:] = sum_e P[e][b] * wbank[e,:,:]
// 512 blocks; each owns TWO 4KB offset-slices (processed sequentially) and
// accumulates all 32 batch outputs in registers while streaming the 64 expert
// slices exactly once. Depth-4 software pipeline (4 loads in flight/wave).
// Exactly 2 blocks/CU x 256 CU = single-round schedule, no ragged tail.
// Bias mixture folded into blocks 0..31 as a prologue.

constexpr int E = 64;
constexpr int K = 8;
constexpr int B = 32;
constexpr int IN_DIM = 1024;
constexpr int OUT_DIM = 1024;

constexpr int NV4      = OUT_DIM * IN_DIM / 4;   // 262,144 float4 per expert
constexpr int BLK      = 256;
constexpr int WBLOCKS  = 512;                    // 2 chunks each
constexpr int WM_ELEMS = B * OUT_DIM * IN_DIM;
constexpr int OB4      = OUT_DIM / 4;            // 256 float4 per bias row
constexpr int BIAS_BLOCKS = (B * OB4) / BLK;     // 32

__global__ __launch_bounds__(BLK) void ParameterMixture_86835648790543_kernel(
    const float* __restrict__ wprobs,   // [B,K]
    const float* __restrict__ bprobs,   // [B,K]
    const int*   __restrict__ widx,     // [B,K]
    const int*   __restrict__ bidx,     // [B,K]
    const float* __restrict__ wbank,    // [E,O,I]
    const float* __restrict__ bbank,    // [E,O]
    float*       __restrict__ out)      // [B*O*I] ++ [B*O]
{
    const int bid = blockIdx.x;
    const int t   = threadIdx.x;

    // ---- build dense P[e][b] in LDS, e-major ----
    __shared__ float sP[E * B];   // 8 KB
    __shared__ float swp[B * K];  // 1 KB
    __shared__ int   swi[B * K];  // 1 KB

    swp[t] = wprobs[t];           // B*K == 256 == BLK
    swi[t] = widx[t];
    __syncthreads();

#pragma unroll
    for (int r = 0; r < (E * B) / BLK; ++r) {
        const int idx = r * BLK + t;
        const int e = idx >> 5;
        const int b = idx & 31;
        float s = 0.f;
#pragma unroll
        for (int k = 0; k < K; ++k)
            s += (swi[b * K + k] == e) ? swp[b * K + k] : 0.f;
        sP[idx] = s;
    }
    __syncthreads();

    // ---- bias prologue on blocks 0..31 (tiny) ----
    if (bid < BIAS_BLOCKS) {
        const int tt   = bid * BLK + t;       // float4 idx into [B,O]
        const int b    = tt / OB4;
        const int off4 = tt % OB4;
        const float4* __restrict__ bb4 = (const float4*)bbank;
        float4 acc = make_float4(0.f, 0.f, 0.f, 0.f);
#pragma unroll
        for (int k = 0; k < K; ++k) {
            const float p = bprobs[b * K + k];
            const int   e = bidx[b * K + k];
            const float4 v = bb4[e * OB4 + off4];
            acc.x += p * v.x; acc.y += p * v.y;
            acc.z += p * v.z; acc.w += p * v.w;
        }
        ((float4*)(out + WM_ELEMS))[tt] = acc;
    }

    // ---- main mixture: two chunks per block ----
    auto process_chunk = [&](int chunk) {
        const int off4 = chunk * BLK + t;                // float4 index in a matrix
        const float4* __restrict__ bp = (const float4*)wbank + off4;

        float4 acc[B];
#pragma unroll
        for (int b = 0; b < B; ++b) acc[b] = make_float4(0.f, 0.f, 0.f, 0.f);

        // depth-4 pipeline: 4 slices in flight, static rotation
        float4 v0 = bp[(size_t)0 * NV4];
        float4 v1 = bp[(size_t)1 * NV4];
        float4 n0 = bp[(size_t)2 * NV4];
        float4 n1 = bp[(size_t)3 * NV4];

#pragma unroll 1
        for (int e = 0; e < E; e += 2) {
            int e4 = e + 4; if (e4 > E - 1) e4 = E - 1;   // uniform clamp (tail re-reads)
            int e5 = e + 5; if (e5 > E - 1) e5 = E - 1;
            const float4 m0 = bp[(size_t)e4 * NV4];
            const float4 m1 = bp[(size_t)e5 * NV4];

            const float4* __restrict__ p0 = (const float4*)&sP[e * B];
            const float4* __restrict__ p1 = (const float4*)&sP[(e + 1) * B];
#pragma unroll
            for (int bq = 0; bq < B / 4; ++bq) {
                const float4 pa = p0[bq];   // broadcast ds_read_b128
                const float4 pb = p1[bq];
#define ACC1(j, pc, vv)                                                        \
                acc[4 * bq + (j)].x += (pc) * (vv).x;                          \
                acc[4 * bq + (j)].y += (pc) * (vv).y;                          \
                acc[4 * bq + (j)].z += (pc) * (vv).z;                          \
                acc[4 * bq + (j)].w += (pc) * (vv).w;
                ACC1(0, pa.x, v0) ACC1(1, pa.y, v0) ACC1(2, pa.z, v0) ACC1(3, pa.w, v0)
                ACC1(0, pb.x, v1) ACC1(1, pb.y, v1) ACC1(2, pb.z, v1) ACC1(3, pb.w, v1)
#undef ACC1
            }
            v0 = n0; v1 = n1; n0 = m0; n1 = m1;
        }

        float4* __restrict__ o4 = (float4*)out + off4;
#pragma unroll
        for (int b = 0; b < B; ++b)
            o4[(size_t)b * NV4] = acc[b];
    };

    process_chunk(bid);
    process_chunk(bid + WBLOCKS);
}

extern "C" void kernel_launch(void* const* d_in, const int* in_sizes, int n_in,
                              void* d_out, int out_size, void* d_ws, size_t ws_size,
                              hipStream_t stream) {
    const float* wprobs = (const float*)d_in[0];
    const float* bprobs = (const float*)d_in[1];
    const int*   widx   = (const int*)d_in[2];
    const int*   bidx   = (const int*)d_in[3];
    const float* wbank  = (const float*)d_in[4];
    const float* bbank  = (const float*)d_in[5];
    float*       out    = (float*)d_out;

    ParameterMixture_86835648790543_kernel<<<WBLOCKS, BLK, 0, stream>>>(
        wprobs, bprobs, widx, bidx, wbank, bbank, out);
}

// Round 5
// 105.618 us; speedup vs baseline: 1.2204x; 1.0094x over previous
//
#include <hip/hip_runtime.h>

// ParameterMixture, expert-major dense mixture, P in SGPRs:
//   P[e][b] = sum_k wprobs[b,k]*(widx[b,k]==e)   (built into d_ws by kernel A)
//   weight_mixture[b,:,:] = sum_e P[e][b] * wbank[e,:,:]
// Main kernel has NO LDS: P rows are read at wave-uniform addresses ->
// scalar s_load pipe; inner loop is pure {global float4 stream + v_fmac}.
// Each block owns two 4KB offset-slices, accumulates all 32 batches in
// registers, streams the 64 expert slices exactly once (256 MB reads,
// 134 MB writes -> ~62us roofline). Depth-4 prefetch, 512-block single round.

constexpr int E = 64;
constexpr int K = 8;
constexpr int B = 32;
constexpr int IN_DIM = 1024;
constexpr int OUT_DIM = 1024;

constexpr int NV4      = OUT_DIM * IN_DIM / 4;   // 262,144 float4 per expert
constexpr int BLK      = 256;
constexpr int WBLOCKS  = 512;                    // 2 chunks each
constexpr int WM_ELEMS = B * OUT_DIM * IN_DIM;
constexpr int OB4      = OUT_DIM / 4;            // 256 float4 per bias row
constexpr int BIAS_BLOCKS = (B * OB4) / BLK;     // 32
constexpr size_t WS_NEEDED = E * B * sizeof(float);  // 8 KB

// ---- kernel A: dense expert-major prob matrix P[e][b] -> d_ws ----
__global__ void ParameterMixture_dense_probs(
    const float* __restrict__ wprobs, const int* __restrict__ widx,
    float* __restrict__ P)
{
    const int t = blockIdx.x * blockDim.x + threadIdx.x;
    if (t >= E * B) return;
    const int e = t >> 5;
    const int b = t & 31;
    float s = 0.f;
#pragma unroll
    for (int k = 0; k < K; ++k)
        s += (widx[b * K + k] == e) ? wprobs[b * K + k] : 0.f;
    P[t] = s;
}

// ---- kernel B: main mixture (no LDS; P via scalar loads) ----
__global__ __launch_bounds__(BLK) void ParameterMixture_86835648790543_kernel(
    const float* __restrict__ wbank,    // [E,O,I]
    const float* __restrict__ P,        // [E,B] dense probs in d_ws
    const float* __restrict__ bprobs,   // [B,K]
    const int*   __restrict__ bidx,     // [B,K]
    const float* __restrict__ bbank,    // [E,O]
    float*       __restrict__ out)      // [B*O*I] ++ [B*O]
{
    const int bid = blockIdx.x;
    const int t   = threadIdx.x;

    // ---- bias prologue on blocks 0..31 (tiny) ----
    if (bid < BIAS_BLOCKS) {
        const int tt   = bid * BLK + t;
        const int b    = tt / OB4;
        const int off4 = tt % OB4;
        const float4* __restrict__ bb4 = (const float4*)bbank;
        float4 acc = make_float4(0.f, 0.f, 0.f, 0.f);
#pragma unroll
        for (int k = 0; k < K; ++k) {
            const float p = bprobs[b * K + k];
            const int   e = bidx[b * K + k];
            const float4 v = bb4[e * OB4 + off4];
            acc.x += p * v.x; acc.y += p * v.y;
            acc.z += p * v.z; acc.w += p * v.w;
        }
        ((float4*)(out + WM_ELEMS))[tt] = acc;
    }

    auto process_chunk = [&](int chunk) {
        const int off4 = chunk * BLK + t;
        const float4* __restrict__ bp = (const float4*)wbank + off4;

        float4 acc[B];
#pragma unroll
        for (int b = 0; b < B; ++b) acc[b] = make_float4(0.f, 0.f, 0.f, 0.f);

        // depth-4 pipeline: 4 slices in flight, static rotation
        float4 v0 = bp[(size_t)0 * NV4];
        float4 v1 = bp[(size_t)1 * NV4];
        float4 n0 = bp[(size_t)2 * NV4];
        float4 n1 = bp[(size_t)3 * NV4];

#pragma unroll 1
        for (int e = 0; e < E; e += 2) {
            int e4 = e + 4; if (e4 > E - 1) e4 = E - 1;
            int e5 = e + 5; if (e5 > E - 1) e5 = E - 1;
            const float4 m0 = bp[(size_t)e4 * NV4];
            const float4 m1 = bp[(size_t)e5 * NV4];

            // Wave-uniform addresses -> scalar s_load (no VALU/LDS cost).
            const float* __restrict__ p0 = P + e * B;
            const float* __restrict__ p1 = P + (e + 1) * B;

#pragma unroll
            for (int b = 0; b < B; ++b) {
                const float pa = p0[b];
                const float pb = p1[b];
                acc[b].x += pa * v0.x; acc[b].y += pa * v0.y;
                acc[b].z += pa * v0.z; acc[b].w += pa * v0.w;
                acc[b].x += pb * v1.x; acc[b].y += pb * v1.y;
                acc[b].z += pb * v1.z; acc[b].w += pb * v1.w;
            }
            v0 = n0; v1 = n1; n0 = m0; n1 = m1;
        }

        float4* __restrict__ o4 = (float4*)out + off4;
#pragma unroll
        for (int b = 0; b < B; ++b)
            o4[(size_t)b * NV4] = acc[b];
    };

    process_chunk(bid);
    process_chunk(bid + WBLOCKS);
}

// ---- fallback (= R4 kernel, LDS-based P) if d_ws is too small ----
__global__ __launch_bounds__(BLK) void ParameterMixture_fallback(
    const float* __restrict__ wprobs, const float* __restrict__ bprobs,
    const int* __restrict__ widx, const int* __restrict__ bidx,
    const float* __restrict__ wbank, const float* __restrict__ bbank,
    float* __restrict__ out)
{
    const int bid = blockIdx.x;
    const int t   = threadIdx.x;

    __shared__ float sP[E * B];
    __shared__ float swp[B * K];
    __shared__ int   swi[B * K];

    swp[t] = wprobs[t];
    swi[t] = widx[t];
    __syncthreads();

#pragma unroll
    for (int r = 0; r < (E * B) / BLK; ++r) {
        const int idx = r * BLK + t;
        const int e = idx >> 5;
        const int b = idx & 31;
        float s = 0.f;
#pragma unroll
        for (int k = 0; k < K; ++k)
            s += (swi[b * K + k] == e) ? swp[b * K + k] : 0.f;
        sP[idx] = s;
    }
    __syncthreads();

    if (bid < BIAS_BLOCKS) {
        const int tt   = bid * BLK + t;
        const int b    = tt / OB4;
        const int off4 = tt % OB4;
        const float4* __restrict__ bb4 = (const float4*)bbank;
        float4 acc = make_float4(0.f, 0.f, 0.f, 0.f);
#pragma unroll
        for (int k = 0; k < K; ++k) {
            const float p = bprobs[b * K + k];
            const int   e = bidx[b * K + k];
            const float4 v = bb4[e * OB4 + off4];
            acc.x += p * v.x; acc.y += p * v.y;
            acc.z += p * v.z; acc.w += p * v.w;
        }
        ((float4*)(out + WM_ELEMS))[tt] = acc;
    }

    auto process_chunk = [&](int chunk) {
        const int off4 = chunk * BLK + t;
        const float4* __restrict__ bp = (const float4*)wbank + off4;
        float4 acc[B];
#pragma unroll
        for (int b = 0; b < B; ++b) acc[b] = make_float4(0.f, 0.f, 0.f, 0.f);
        float4 v0 = bp[(size_t)0 * NV4];
        float4 v1 = bp[(size_t)1 * NV4];
        float4 n0 = bp[(size_t)2 * NV4];
        float4 n1 = bp[(size_t)3 * NV4];
#pragma unroll 1
        for (int e = 0; e < E; e += 2) {
            int e4 = e + 4; if (e4 > E - 1) e4 = E - 1;
            int e5 = e + 5; if (e5 > E - 1) e5 = E - 1;
            const float4 m0 = bp[(size_t)e4 * NV4];
            const float4 m1 = bp[(size_t)e5 * NV4];
            const float4* __restrict__ p0 = (const float4*)&sP[e * B];
            const float4* __restrict__ p1 = (const float4*)&sP[(e + 1) * B];
#pragma unroll
            for (int bq = 0; bq < B / 4; ++bq) {
                const float4 pa = p0[bq];
                const float4 pb = p1[bq];
#define ACC1(j, pc, vv)                                                        \
                acc[4 * bq + (j)].x += (pc) * (vv).x;                          \
                acc[4 * bq + (j)].y += (pc) * (vv).y;                          \
                acc[4 * bq + (j)].z += (pc) * (vv).z;                          \
                acc[4 * bq + (j)].w += (pc) * (vv).w;
                ACC1(0, pa.x, v0) ACC1(1, pa.y, v0) ACC1(2, pa.z, v0) ACC1(3, pa.w, v0)
                ACC1(0, pb.x, v1) ACC1(1, pb.y, v1) ACC1(2, pb.z, v1) ACC1(3, pb.w, v1)
#undef ACC1
            }
            v0 = n0; v1 = n1; n0 = m0; n1 = m1;
        }
        float4* __restrict__ o4 = (float4*)out + off4;
#pragma unroll
        for (int b = 0; b < B; ++b)
            o4[(size_t)b * NV4] = acc[b];
    };

    process_chunk(bid);
    process_chunk(bid + WBLOCKS);
}

extern "C" void kernel_launch(void* const* d_in, const int* in_sizes, int n_in,
                              void* d_out, int out_size, void* d_ws, size_t ws_size,
                              hipStream_t stream) {
    const float* wprobs = (const float*)d_in[0];
    const float* bprobs = (const float*)d_in[1];
    const int*   widx   = (const int*)d_in[2];
    const int*   bidx   = (const int*)d_in[3];
    const float* wbank  = (const float*)d_in[4];
    const float* bbank  = (const float*)d_in[5];
    float*       out    = (float*)d_out;

    if (ws_size >= WS_NEEDED) {
        float* P = (float*)d_ws;
        ParameterMixture_dense_probs<<<(E * B + BLK - 1) / BLK, BLK, 0, stream>>>(
            wprobs, widx, P);
        ParameterMixture_86835648790543_kernel<<<WBLOCKS, BLK, 0, stream>>>(
            wbank, P, bprobs, bidx, bbank, out);
    } else {
        ParameterMixture_fallback<<<WBLOCKS, BLK, 0, stream>>>(
            wprobs, bprobs, widx, bidx, wbank, bbank, out);
    }
}

// Round 6
// 93.833 us; speedup vs baseline: 1.3736x; 1.1256x over previous
//
#include <hip/hip_runtime.h>
#include <hip/hip_bf16.h>

// ParameterMixture as a thin GEMM on the matrix cores:
//   C[32 batches x 1M cols] = P[32 x 64] @ W[64 x 1M]   (W = wbank viewed [E, O*I])
// v_mfma_f32_32x32x16_bf16, fp32 accuracy restored via split compensation:
//   P = Ph + Pl, W = Wh + Wl (bf16 hi/lo);  C ~= Ph*Wh + Ph*Wl + Pl*Wh
//   (dropped Pl*Wl ~ 2^-18 rel; threshold is 4.57e-3 -> huge margin)
// A-fragments (P, tiny) precomputed in MFMA lane layout into d_ws (8 KB).
// Main kernel: no LDS, no barriers; per wave-step: 32 column-mode dword loads
// (128B full cachelines, each line touched exactly once chip-wide), ~130 VALU
// cvt, 12 MFMA, 16 dword stores. acc = 16 VGPR -> 4 blocks/CU, 16 waves/CU.
//
// Layouts (gfx950, 32x32x16 bf16):
//   C/D (verified m74/m101): col = lane&31, row = (reg&3) + 8*(reg>>2) + 4*(lane>>5)
//   A (M=32 x K=16):  row = lane&31, k = 8*(lane>>5) + j   (j = frag element 0..7)
//   B (K=16 x N=32):  col = lane&31, k = 8*(lane>>5) + j

typedef __attribute__((ext_vector_type(8)))  short short8v;
typedef __attribute__((ext_vector_type(16))) float f32x16;

constexpr int E = 64;
constexpr int K = 8;
constexpr int B = 32;
constexpr int IN_DIM = 1024;
constexpr int OUT_DIM = 1024;

constexpr int    NCOL     = OUT_DIM * IN_DIM;     // 1,048,576 cols of W-matrix
constexpr int    BLK      = 256;
constexpr int    GRID     = 1024;                 // 4 blocks/CU, single round
constexpr int    WAVES    = GRID * 4;             // 4096 waves
constexpr int    CGROUPS  = NCOL / 32;            // 32,768 col-groups
constexpr int    STEPS    = CGROUPS / WAVES;      // 8 (exact, no tail)
constexpr int    WM_ELEMS = B * NCOL;
constexpr int    OB4      = OUT_DIM / 4;          // 256
constexpr size_t WS_NEEDED = 2 * 4 * 64 * 8 * sizeof(short);  // 8 KB

// ---- kernel A: build A-fragments (P in MFMA lane layout, bf16 hi + lo) ----
// afrag layout: [hi/lo][s=0..3][lane=0..63][j=0..7] shorts
__global__ void ParameterMixture_build_afrag(
    const float* __restrict__ wprobs,   // [B,K]
    const int*   __restrict__ widx,     // [B,K]
    short*       __restrict__ afrag)
{
    const int t    = threadIdx.x;       // one block of 256: t = s*64 + lane
    const int s    = t >> 6;            // K-step (16 experts each)
    const int lane = t & 63;
    const int m    = lane & 31;         // batch (A row)
    const int kh   = (lane >> 5) * 8;   // k half-offset

#pragma unroll
    for (int j = 0; j < 8; ++j) {
        const int e = s * 16 + kh + j;  // expert (A col / K index)
        float p = 0.f;
#pragma unroll
        for (int k2 = 0; k2 < K; ++k2)
            p += (widx[m * K + k2] == e) ? wprobs[m * K + k2] : 0.f;
        const __hip_bfloat16 h  = __float2bfloat16(p);
        const float          hf = __bfloat162float(h);
        const __hip_bfloat16 l  = __float2bfloat16(p - hf);
        afrag[(0 * 4 + s) * 512 + lane * 8 + j] = __builtin_bit_cast(short, h);
        afrag[(1 * 4 + s) * 512 + lane * 8 + j] = __builtin_bit_cast(short, l);
    }
}

// ---- kernel B: MFMA mixture ----
__global__ __launch_bounds__(BLK, 4) void ParameterMixture_86835648790543_kernel(
    const float* __restrict__ wbank,    // [E, NCOL]
    const short* __restrict__ afrag,    // d_ws
    const float* __restrict__ bprobs,   // [B,K]
    const int*   __restrict__ bidx,     // [B,K]
    const float* __restrict__ bbank,    // [E,O]
    float*       __restrict__ out)      // [B*NCOL] ++ [B*O]
{
    const int bid  = blockIdx.x;
    const int t    = threadIdx.x;
    const int wv   = t >> 6;
    const int lane = t & 63;

    // ---- bias prologue on blocks 0..31 (tiny, fp32 exact) ----
    if (bid < 32) {
        const int tt   = bid * BLK + t;     // float4 idx into [B,O]
        const int b    = tt / OB4;
        const int off4 = tt % OB4;
        const float4* __restrict__ bb4 = (const float4*)bbank;
        float4 a4 = make_float4(0.f, 0.f, 0.f, 0.f);
#pragma unroll
        for (int k = 0; k < K; ++k) {
            const float p = bprobs[b * K + k];
            const int   e = bidx[b * K + k];
            const float4 v = bb4[e * OB4 + off4];
            a4.x += p * v.x; a4.y += p * v.y;
            a4.z += p * v.z; a4.w += p * v.w;
        }
        ((float4*)(out + WM_ELEMS))[tt] = a4;
    }

    // ---- load A-fragments (8 x 16B per lane, shared by all steps) ----
    short8v aH[4], aL[4];
#pragma unroll
    for (int s = 0; s < 4; ++s) {
        aH[s] = *(const short8v*)(afrag + s * 512 + lane * 8);
        aL[s] = *(const short8v*)(afrag + 2048 + s * 512 + lane * 8);
    }

    const int    cl   = lane & 31;        // B/C column within group
    const int    kh   = (lane >> 5) * 8;  // k half-offset
    const size_t ncol = (size_t)NCOL;

    for (int step = 0; step < STEPS; ++step) {
        const int col0 = ((bid * 4 + wv) + step * WAVES) * 32;
        const float* __restrict__ wcol = wbank + col0 + cl;

        // issue all 32 column-mode loads (kept in flight together)
        float w[4][8];
#pragma unroll
        for (int s = 0; s < 4; ++s)
#pragma unroll
            for (int j = 0; j < 8; ++j)
                w[s][j] = wcol[(size_t)(s * 16 + kh + j) * ncol];

        f32x16 acc;
#pragma unroll
        for (int i = 0; i < 16; ++i) acc[i] = 0.f;

#pragma unroll
        for (int s = 0; s < 4; ++s) {
            short8v bh, bl;
#pragma unroll
            for (int j = 0; j < 8; ++j) {
                const float x = w[s][j];
                const __hip_bfloat16 h  = __float2bfloat16(x);
                const float          hf = __bfloat162float(h);
                const __hip_bfloat16 l  = __float2bfloat16(x - hf);
                bh[j] = __builtin_bit_cast(short, h);
                bl[j] = __builtin_bit_cast(short, l);
            }
            acc = __builtin_amdgcn_mfma_f32_32x32x16_bf16(aH[s], bh, acc, 0, 0, 0);
            acc = __builtin_amdgcn_mfma_f32_32x32x16_bf16(aH[s], bl, acc, 0, 0, 0);
            acc = __builtin_amdgcn_mfma_f32_32x32x16_bf16(aL[s], bh, acc, 0, 0, 0);
        }

        // store C-tile: row = (reg&3) + 8*(reg>>2) + 4*(lane>>5)
        float* __restrict__ ob = out + (size_t)((lane >> 5) * 4) * ncol + col0 + cl;
#pragma unroll
        for (int reg = 0; reg < 16; ++reg) {
            const int row = (reg & 3) + 8 * (reg >> 2);
            ob[(size_t)row * ncol] = acc[reg];
        }
    }
}

extern "C" void kernel_launch(void* const* d_in, const int* in_sizes, int n_in,
                              void* d_out, int out_size, void* d_ws, size_t ws_size,
                              hipStream_t stream) {
    const float* wprobs = (const float*)d_in[0];
    const float* bprobs = (const float*)d_in[1];
    const int*   widx   = (const int*)d_in[2];
    const int*   bidx   = (const int*)d_in[3];
    const float* wbank  = (const float*)d_in[4];
    const float* bbank  = (const float*)d_in[5];
    float*       out    = (float*)d_out;

    short* afrag = (short*)d_ws;   // d_ws is ~1 GiB (poison fill evidence); need 8 KB

    ParameterMixture_build_afrag<<<1, BLK, 0, stream>>>(wprobs, widx, afrag);
    ParameterMixture_86835648790543_kernel<<<GRID, BLK, 0, stream>>>(
        wbank, afrag, bprobs, bidx, bbank, out);
}